// Round 6
// baseline (405.649 us; speedup 1.0000x reference)
//
#include <hip/hip_runtime.h>
#include <hip/hip_bf16.h>

#define NN 32768      // nodes total
#define EE 524288     // edges total
#define HID 128
#define BGRAPH 64
#define MAXN 512
#define AOUT 512
#define MAXDEG 64     // per-node degree cap (Poisson(16): P(deg>64) ~ 1e-18)

typedef __attribute__((address_space(1))) const unsigned int ga_u32;
typedef __attribute__((address_space(3))) unsigned int lds_u32;

// ---------------- direct bucket build (no CSR scan) ----------------
__global__ void scatter_direct(const int* __restrict__ src, const int* __restrict__ dst,
                               int* __restrict__ cursor, int* __restrict__ bucket) {
    int i = blockIdx.x * blockDim.x + threadIdx.x;
    if (i < EE) {
        int d = dst[i];
        int p = atomicAdd(&cursor[d], 1);
        if (p < MAXDEG) bucket[(size_t)d * MAXDEG + p] = src[i];
    }
}

// ---------------- layer-0 transform (K=12, single chunk) ----------------
template<int KTOT, int KC, int CHUNKS>
__global__ __launch_bounds__(256) void transform3(
    const float* __restrict__ hin, const float* __restrict__ Wl,
    const float* __restrict__ Wr, float* __restrict__ xl, float* __restrict__ xr) {
    __shared__ float wb[2][KC][256];
    __shared__ float ha[2][KC][36];
    int b = blockIdx.x;
    int xcd = b & 7, slot = b >> 3;
    int graph = xcd + 8 * (slot >> 4);
    int chunk = slot & 15;
    int node0 = graph * 512 + chunk * 32;
    int t = threadIdx.x;
    int c32 = t & 31;
    int ng  = t >> 5;
    const float4* wl4g = (const float4*)Wl;
    const float4* wr4g = (const float4*)Wr;
    for (int idx = t; idx < KC * 64; idx += 256) {
        int k = idx >> 6, r = idx & 63;
        float4 v = (r < 32) ? wl4g[k * 32 + r] : wr4g[k * 32 + (r - 32)];
        ((float4*)&wb[0][k][0])[r] = v;
    }
    for (int idx = t; idx < 32 * KC; idx += 256) {
        int m = idx / KC, kk = idx - m * KC;
        ha[0][kk][m] = hin[(size_t)(node0 + m) * KTOT + kk];
    }
    __syncthreads();
    float4 accL[4], accR[4];
#pragma unroll
    for (int m = 0; m < 4; m++) {
        accL[m].x = accL[m].y = accL[m].z = accL[m].w = 0.f;
        accR[m].x = accR[m].y = accR[m].z = accR[m].w = 0.f;
    }
#pragma unroll
    for (int kk = 0; kk < KC; kk++) {
        float4 wl = ((const float4*)&wb[0][kk][0])[c32];
        float4 wr = ((const float4*)&wb[0][kk][128])[c32];
        float4 hv = *(const float4*)&ha[0][kk][ng * 4];
        accL[0].x = fmaf(hv.x, wl.x, accL[0].x); accL[0].y = fmaf(hv.x, wl.y, accL[0].y);
        accL[0].z = fmaf(hv.x, wl.z, accL[0].z); accL[0].w = fmaf(hv.x, wl.w, accL[0].w);
        accL[1].x = fmaf(hv.y, wl.x, accL[1].x); accL[1].y = fmaf(hv.y, wl.y, accL[1].y);
        accL[1].z = fmaf(hv.y, wl.z, accL[1].z); accL[1].w = fmaf(hv.y, wl.w, accL[1].w);
        accL[2].x = fmaf(hv.z, wl.x, accL[2].x); accL[2].y = fmaf(hv.z, wl.y, accL[2].y);
        accL[2].z = fmaf(hv.z, wl.z, accL[2].z); accL[2].w = fmaf(hv.z, wl.w, accL[2].w);
        accL[3].x = fmaf(hv.w, wl.x, accL[3].x); accL[3].y = fmaf(hv.w, wl.y, accL[3].y);
        accL[3].z = fmaf(hv.w, wl.z, accL[3].z); accL[3].w = fmaf(hv.w, wl.w, accL[3].w);
        accR[0].x = fmaf(hv.x, wr.x, accR[0].x); accR[0].y = fmaf(hv.x, wr.y, accR[0].y);
        accR[0].z = fmaf(hv.x, wr.z, accR[0].z); accR[0].w = fmaf(hv.x, wr.w, accR[0].w);
        accR[1].x = fmaf(hv.y, wr.x, accR[1].x); accR[1].y = fmaf(hv.y, wr.y, accR[1].y);
        accR[1].z = fmaf(hv.y, wr.z, accR[1].z); accR[1].w = fmaf(hv.y, wr.w, accR[1].w);
        accR[2].x = fmaf(hv.z, wr.x, accR[2].x); accR[2].y = fmaf(hv.z, wr.y, accR[2].y);
        accR[2].z = fmaf(hv.z, wr.z, accR[2].z); accR[2].w = fmaf(hv.z, wr.w, accR[2].w);
        accR[3].x = fmaf(hv.w, wr.x, accR[3].x); accR[3].y = fmaf(hv.w, wr.y, accR[3].y);
        accR[3].z = fmaf(hv.w, wr.z, accR[3].z); accR[3].w = fmaf(hv.w, wr.w, accR[3].w);
    }
    float4* xlo = (float4*)xl;
    float4* xro = (float4*)xr;
#pragma unroll
    for (int m = 0; m < 4; m++) {
        int n = node0 + ng * 4 + m;
        xlo[n * 32 + c32] = accL[m];
        xro[n * 32 + c32] = accR[m];
    }
}

// ---------------- main transform (K=128): async-DMA W staging ----------------
// 512 thr / 64 nodes / block; KC=16 double-buffered. W chunks go global->LDS
// via global_load_lds (16B) so the wait lands on the barrier, not mid-stage.
// h tile: 2 floats/thread via regs, ds_write AFTER compute.
__global__ __launch_bounds__(512) void transform4(
    const float* __restrict__ hin, const float* __restrict__ Wl,
    const float* __restrict__ Wr, float* __restrict__ xl, float* __restrict__ xr) {
    __shared__ float wlb[2][16][128];   // 16 KB
    __shared__ float wrb[2][16][128];   // 16 KB
    __shared__ float ha[2][16][68];     // transposed h tile, pad 68 (8.5 KB)
    int b = blockIdx.x;                 // 512 blocks
    int xcd = b & 7, slot = b >> 3;
    int graph = xcd + 8 * (slot >> 3);
    int chunk = slot & 7;
    int node0 = graph * 512 + chunk * 64;
    int t = threadIdx.x;
    int w = t >> 6, lane = t & 63;
    int c32 = t & 31, ng = t >> 5;      // ng 0..15 -> nodes ng*4..+3

    float h0, h1;
    int i0 = t, i1 = t + 512;
    int m0 = i0 >> 4, k0 = i0 & 15;
    int m1 = i1 >> 4, k1 = i1 & 15;

    auto loadH = [&](int kc) {
        h0 = hin[(size_t)(node0 + m0) * 128 + kc + k0];
        h1 = hin[(size_t)(node0 + m1) * 128 + kc + k1];
    };
    auto writeH = [&](int buf) {
        ha[buf][k0][m0] = h0;
        ha[buf][k1][m1] = h1;
    };
    auto dmaW = [&](int buf, int kc) {
        // wave w copies its 1KB segment of each 8KB chunk (lane*16B auto-offset)
        const float* gl = Wl + kc * 128 + w * 256 + lane * 4;
        const float* gr = Wr + kc * 128 + w * 256 + lane * 4;
        float* ll = &wlb[buf][0][0] + w * 256;
        float* lr = &wrb[buf][0][0] + w * 256;
        __builtin_amdgcn_global_load_lds((ga_u32*)gl, (lds_u32*)ll, 16, 0, 0);
        __builtin_amdgcn_global_load_lds((ga_u32*)gr, (lds_u32*)lr, 16, 0, 0);
    };

    float4 accL[4], accR[4];
#pragma unroll
    for (int m = 0; m < 4; m++) {
        accL[m].x = accL[m].y = accL[m].z = accL[m].w = 0.f;
        accR[m].x = accR[m].y = accR[m].z = accR[m].w = 0.f;
    }

    loadH(0);
    dmaW(0, 0);
    writeH(0);
    __syncthreads();
    int buf = 0;
    for (int c = 0; c < 8; c++) {
        if (c < 7) { loadH((c + 1) * 16); dmaW(buf ^ 1, (c + 1) * 16); }
#pragma unroll
        for (int kk = 0; kk < 16; kk++) {
            float4 wl = *(const float4*)&wlb[buf][kk][c32 * 4];
            float4 wr = *(const float4*)&wrb[buf][kk][c32 * 4];
            float4 hv = *(const float4*)&ha[buf][kk][ng * 4];
            accL[0].x = fmaf(hv.x, wl.x, accL[0].x); accL[0].y = fmaf(hv.x, wl.y, accL[0].y);
            accL[0].z = fmaf(hv.x, wl.z, accL[0].z); accL[0].w = fmaf(hv.x, wl.w, accL[0].w);
            accL[1].x = fmaf(hv.y, wl.x, accL[1].x); accL[1].y = fmaf(hv.y, wl.y, accL[1].y);
            accL[1].z = fmaf(hv.y, wl.z, accL[1].z); accL[1].w = fmaf(hv.y, wl.w, accL[1].w);
            accL[2].x = fmaf(hv.z, wl.x, accL[2].x); accL[2].y = fmaf(hv.z, wl.y, accL[2].y);
            accL[2].z = fmaf(hv.z, wl.z, accL[2].z); accL[2].w = fmaf(hv.z, wl.w, accL[2].w);
            accL[3].x = fmaf(hv.w, wl.x, accL[3].x); accL[3].y = fmaf(hv.w, wl.y, accL[3].y);
            accL[3].z = fmaf(hv.w, wl.z, accL[3].z); accL[3].w = fmaf(hv.w, wl.w, accL[3].w);
            accR[0].x = fmaf(hv.x, wr.x, accR[0].x); accR[0].y = fmaf(hv.x, wr.y, accR[0].y);
            accR[0].z = fmaf(hv.x, wr.z, accR[0].z); accR[0].w = fmaf(hv.x, wr.w, accR[0].w);
            accR[1].x = fmaf(hv.y, wr.x, accR[1].x); accR[1].y = fmaf(hv.y, wr.y, accR[1].y);
            accR[1].z = fmaf(hv.y, wr.z, accR[1].z); accR[1].w = fmaf(hv.y, wr.w, accR[1].w);
            accR[2].x = fmaf(hv.z, wr.x, accR[2].x); accR[2].y = fmaf(hv.z, wr.y, accR[2].y);
            accR[2].z = fmaf(hv.z, wr.z, accR[2].z); accR[2].w = fmaf(hv.z, wr.w, accR[2].w);
            accR[3].x = fmaf(hv.w, wr.x, accR[3].x); accR[3].y = fmaf(hv.w, wr.y, accR[3].y);
            accR[3].z = fmaf(hv.w, wr.z, accR[3].z); accR[3].w = fmaf(hv.w, wr.w, accR[3].w);
        }
        if (c < 7) writeH(buf ^ 1);
        __syncthreads();
        buf ^= 1;
    }

    float4* xlo = (float4*)xl;
    float4* xro = (float4*)xr;
#pragma unroll
    for (int m = 0; m < 4; m++) {
        int n = node0 + ng * 4 + m;
        xlo[n * 32 + c32] = accL[m];
        xro[n * 32 + c32] = accR[m];
    }
}

// ---------------- GATv2 aggregate: idx-preload + v double-buffer ----------
// Wave per 4 nodes (fully unrolled). lane = el*8 + part. Per node: chunk
// indices preloaded (4), v-rows double-buffered (next chunk's gather issues
// before current compute), next node's xr/idx issued before the reduce.
__global__ __launch_bounds__(256) void gat_aggregate5(
    const float* __restrict__ xl, const float* __restrict__ xr,
    const int* __restrict__ bucket, const int* __restrict__ cnt,
    const float* __restrict__ att, const float* __restrict__ bias,
    float* __restrict__ hout) {
    int b = blockIdx.x;                 // 2048 blocks
    int xcd = b & 7, slot = b >> 3;
    int graph = xcd + 8 * (slot >> 5);
    int chunk = slot & 31;
    int wid = threadIdx.x >> 6;
    int lane = threadIdx.x & 63;
    int n0 = graph * 512 + chunk * 16 + wid * 4;
    int el = lane >> 3;
    int part = lane & 7;

    const float4* xl4 = (const float4*)xl;
    const float4* xr4 = (const float4*)xr;
    const float4* att4 = (const float4*)att;
    const float4* bias4 = (const float4*)bias;
    float4* out4 = (float4*)hout;
    float4 atv[4], bv[4];
#pragma unroll
    for (int i = 0; i < 4; i++) {
        atv[i] = att4[part * 4 + i];
        bv[i] = bias4[part * 4 + i];
    }
    int4 cnts = *(const int4*)&cnt[n0];
    float4 xrv[4];
    int idx[4];
#pragma unroll
    for (int i = 0; i < 4; i++) xrv[i] = xr4[(size_t)n0 * 32 + part * 4 + i];
#pragma unroll
    for (int c = 0; c < 4; c++) idx[c] = bucket[(size_t)n0 * MAXDEG + c * 8 + el];

#pragma unroll
    for (int ni = 0; ni < 4; ni++) {
        int n = n0 + ni;
        int nE = (ni == 0) ? cnts.x : (ni == 1) ? cnts.y : (ni == 2) ? cnts.z : cnts.w;
        nE = (nE > MAXDEG) ? MAXDEG : nE;
        int nC = (nE + 7) >> 3;
        float4 acc[4];
#pragma unroll
        for (int i = 0; i < 4; i++) { acc[i].x = 0.f; acc[i].y = 0.f; acc[i].z = 0.f; acc[i].w = 0.f; }
        float den = 0.f;
        int s0 = (el < nE) ? idx[0] : n;
        float4 v[4];
        {
            const float4* row = xl4 + (size_t)s0 * 32 + part * 4;
#pragma unroll
            for (int i = 0; i < 4; i++) v[i] = row[i];
        }
        for (int c = 0; c < nC; c++) {
            float4 vn[4];
            if (c + 1 < nC) {
                int raw = (c + 1 < 4) ? idx[c + 1] : bucket[(size_t)n * MAXDEG + (c + 1) * 8 + el];
                int sn = ((c + 1) * 8 + el < nE) ? raw : n;
                const float4* rown = xl4 + (size_t)sn * 32 + part * 4;
#pragma unroll
                for (int i = 0; i < 4; i++) vn[i] = rown[i];
            }
            float t = 0.f, u, lr;
            u = v[0].x + xrv[0].x; lr = fmaf(0.2f, fminf(u, 0.f), fmaxf(u, 0.f)); t = fmaf(atv[0].x, lr, t);
            u = v[0].y + xrv[0].y; lr = fmaf(0.2f, fminf(u, 0.f), fmaxf(u, 0.f)); t = fmaf(atv[0].y, lr, t);
            u = v[0].z + xrv[0].z; lr = fmaf(0.2f, fminf(u, 0.f), fmaxf(u, 0.f)); t = fmaf(atv[0].z, lr, t);
            u = v[0].w + xrv[0].w; lr = fmaf(0.2f, fminf(u, 0.f), fmaxf(u, 0.f)); t = fmaf(atv[0].w, lr, t);
            u = v[1].x + xrv[1].x; lr = fmaf(0.2f, fminf(u, 0.f), fmaxf(u, 0.f)); t = fmaf(atv[1].x, lr, t);
            u = v[1].y + xrv[1].y; lr = fmaf(0.2f, fminf(u, 0.f), fmaxf(u, 0.f)); t = fmaf(atv[1].y, lr, t);
            u = v[1].z + xrv[1].z; lr = fmaf(0.2f, fminf(u, 0.f), fmaxf(u, 0.f)); t = fmaf(atv[1].z, lr, t);
            u = v[1].w + xrv[1].w; lr = fmaf(0.2f, fminf(u, 0.f), fmaxf(u, 0.f)); t = fmaf(atv[1].w, lr, t);
            u = v[2].x + xrv[2].x; lr = fmaf(0.2f, fminf(u, 0.f), fmaxf(u, 0.f)); t = fmaf(atv[2].x, lr, t);
            u = v[2].y + xrv[2].y; lr = fmaf(0.2f, fminf(u, 0.f), fmaxf(u, 0.f)); t = fmaf(atv[2].y, lr, t);
            u = v[2].z + xrv[2].z; lr = fmaf(0.2f, fminf(u, 0.f), fmaxf(u, 0.f)); t = fmaf(atv[2].z, lr, t);
            u = v[2].w + xrv[2].w; lr = fmaf(0.2f, fminf(u, 0.f), fmaxf(u, 0.f)); t = fmaf(atv[2].w, lr, t);
            u = v[3].x + xrv[3].x; lr = fmaf(0.2f, fminf(u, 0.f), fmaxf(u, 0.f)); t = fmaf(atv[3].x, lr, t);
            u = v[3].y + xrv[3].y; lr = fmaf(0.2f, fminf(u, 0.f), fmaxf(u, 0.f)); t = fmaf(atv[3].y, lr, t);
            u = v[3].z + xrv[3].z; lr = fmaf(0.2f, fminf(u, 0.f), fmaxf(u, 0.f)); t = fmaf(atv[3].z, lr, t);
            u = v[3].w + xrv[3].w; lr = fmaf(0.2f, fminf(u, 0.f), fmaxf(u, 0.f)); t = fmaf(atv[3].w, lr, t);
            t += __shfl_xor(t, 1);
            float a = (c * 8 + el < nE) ? __expf(t) : 0.f;
            den += a;
            acc[0].x = fmaf(a, v[0].x, acc[0].x); acc[0].y = fmaf(a, v[0].y, acc[0].y);
            acc[0].z = fmaf(a, v[0].z, acc[0].z); acc[0].w = fmaf(a, v[0].w, acc[0].w);
            acc[1].x = fmaf(a, v[1].x, acc[1].x); acc[1].y = fmaf(a, v[1].y, acc[1].y);
            acc[1].z = fmaf(a, v[1].z, acc[1].z); acc[1].w = fmaf(a, v[1].w, acc[1].w);
            acc[2].x = fmaf(a, v[2].x, acc[2].x); acc[2].y = fmaf(a, v[2].y, acc[2].y);
            acc[2].z = fmaf(a, v[2].z, acc[2].z); acc[2].w = fmaf(a, v[2].w, acc[2].w);
            acc[3].x = fmaf(a, v[3].x, acc[3].x); acc[3].y = fmaf(a, v[3].y, acc[3].y);
            acc[3].z = fmaf(a, v[3].z, acc[3].z); acc[3].w = fmaf(a, v[3].w, acc[3].w);
            if (c + 1 < nC) {
#pragma unroll
                for (int i = 0; i < 4; i++) v[i] = vn[i];
            }
        }
        // issue next node's xr + idx before the reduce (overlap latency)
        if (ni < 3) {
#pragma unroll
            for (int i = 0; i < 4; i++) xrv[i] = xr4[(size_t)(n + 1) * 32 + part * 4 + i];
#pragma unroll
            for (int c = 0; c < 4; c++) idx[c] = bucket[(size_t)(n + 1) * MAXDEG + c * 8 + el];
        }
#pragma unroll
        for (int m = 8; m <= 32; m <<= 1) {
#pragma unroll
            for (int i = 0; i < 4; i++) {
                acc[i].x += __shfl_xor(acc[i].x, m);
                acc[i].y += __shfl_xor(acc[i].y, m);
                acc[i].z += __shfl_xor(acc[i].z, m);
                acc[i].w += __shfl_xor(acc[i].w, m);
            }
            den += __shfl_xor(den, m);
        }
        if (el == 0) {
            float rden = 1.0f / fmaxf(den, 1e-16f);
#pragma unroll
            for (int i = 0; i < 4; i++) {
                float4 o;
                o.x = fmaxf(fmaf(acc[i].x, rden, bv[i].x), 0.f);
                o.y = fmaxf(fmaf(acc[i].y, rden, bv[i].y), 0.f);
                o.z = fmaxf(fmaf(acc[i].z, rden, bv[i].z), 0.f);
                o.w = fmaxf(fmaf(acc[i].w, rden, bv[i].w), 0.f);
                out4[(size_t)n * 32 + part * 4 + i] = o;
            }
        }
    }
}

// ---------------- pooling stage 1 ----------------
__global__ __launch_bounds__(128) void pool_partial(const float* __restrict__ h,
                                                    float* __restrict__ psum,
                                                    float* __restrict__ pmax) {
    int g = blockIdx.x >> 3;
    int c = blockIdx.x & 7;
    int d = threadIdx.x;
    const float* base = h + (size_t)(g * MAXN + c * 64) * 128;
    float s = 0.f, m = -1e30f;
    for (int i = 0; i < 64; i++) {
        float v = base[i * 128 + d];
        s += v;
        m = fmaxf(m, v);
    }
    psum[blockIdx.x * 128 + d] = s;
    pmax[blockIdx.x * 128 + d] = m;
}

// ---------------- pool-final + dueling head, one block per graph ----------------
__global__ __launch_bounds__(512) void head_kernel(
    const float* __restrict__ psum, const float* __restrict__ pmax,
    const float* __restrict__ qW1, const float* __restrict__ qb1,
    const float* __restrict__ qW2, const float* __restrict__ qb2,
    const float* __restrict__ vW1, const float* __restrict__ vb1,
    const float* __restrict__ vW2, const float* __restrict__ vb2,
    float* __restrict__ qout) {
    __shared__ float gs[256];
    __shared__ float hq[128];
    __shared__ float hv[128];
    __shared__ float red[512];
    int b = blockIdx.x, t = threadIdx.x;
    if (t < 128) {
        float s = 0.f, m = -1e30f;
#pragma unroll
        for (int c = 0; c < 8; c++) {
            s += psum[(b * 8 + c) * 128 + t];
            m = fmaxf(m, pmax[(b * 8 + c) * 128 + t]);
        }
        gs[t] = s * (1.0f / 512.0f);
        gs[128 + t] = m;
    }
    __syncthreads();
    if (t < 128) {
        float acc = qb1[t];
        for (int k = 0; k < 256; k++) acc = fmaf(gs[k], qW1[k * 128 + t], acc);
        hq[t] = fmaxf(acc, 0.f);
    } else if (t < 256) {
        int tt = t - 128;
        float acc = vb1[tt];
        for (int k = 0; k < 256; k++) acc = fmaf(gs[k], vW1[k * 128 + tt], acc);
        hv[tt] = fmaxf(acc, 0.f);
    }
    __syncthreads();
    float adv = qb2[t];
    for (int k = 0; k < 128; k++) adv = fmaf(hq[k], qW2[k * 512 + t], adv);
    red[t] = (t < 128) ? hv[t] * vW2[t] : 0.f;
    __syncthreads();
    for (int off = 256; off > 0; off >>= 1) {
        if (t < off) red[t] += red[t + off];
        __syncthreads();
    }
    float val = red[0] + vb2[0];
    __syncthreads();
    red[t] = adv;
    __syncthreads();
    for (int off = 256; off > 0; off >>= 1) {
        if (t < off) red[t] += red[t + off];
        __syncthreads();
    }
    float mean_adv = red[0] * (1.0f / 512.0f);
    qout[b * 512 + t] = val + adv - mean_adv;
}

extern "C" void kernel_launch(void* const* d_in, const int* in_sizes, int n_in,
                              void* d_out, int out_size, void* d_ws, size_t ws_size,
                              hipStream_t stream) {
    const float* x        = (const float*)d_in[0];
    const int* edge_src   = (const int*)d_in[1];
    const int* edge_dst   = (const int*)d_in[2];
    const float* Wl0 = (const float*)d_in[4];
    const float* Wr0 = (const float*)d_in[5];
    const float* att0 = (const float*)d_in[6];
    const float* b0 = (const float*)d_in[7];
    const float* Wl = (const float*)d_in[8];
    const float* Wr = (const float*)d_in[9];
    const float* att = (const float*)d_in[10];
    const float* bb = (const float*)d_in[11];
    const float* qW1 = (const float*)d_in[12];
    const float* qb1 = (const float*)d_in[13];
    const float* qW2 = (const float*)d_in[14];
    const float* qb2 = (const float*)d_in[15];
    const float* vW1 = (const float*)d_in[16];
    const float* vb1 = (const float*)d_in[17];
    const float* vW2 = (const float*)d_in[18];
    const float* vb2 = (const float*)d_in[19];

    int* cursor  = (int*)d_ws;                 // NN
    int* bucket  = cursor + NN;                // NN*MAXDEG (8 MB)
    float* fbase = (float*)(bucket + (size_t)NN * MAXDEG);
    float* hbuf0 = fbase;                      // NN*128
    float* hbuf1 = hbuf0 + NN * 128;
    float* xl    = hbuf1 + NN * 128;
    float* xr    = xl + NN * 128;
    float* psum  = xr + NN * 128;
    float* pmax  = psum + BGRAPH * 8 * 128;

    hipMemsetAsync(cursor, 0, NN * sizeof(int), stream);
    scatter_direct<<<EE / 256, 256, 0, stream>>>(edge_src, edge_dst, cursor, bucket);

    transform3<12, 12, 1><<<NN / 32, 256, 0, stream>>>(x, Wl0, Wr0, xl, xr);
    gat_aggregate5<<<NN / 16, 256, 0, stream>>>(xl, xr, bucket, cursor, att0, b0, hbuf0);

    float* hc = hbuf0;
    float* hn = hbuf1;
    for (int i = 0; i < 3; i++) {
        transform4<<<NN / 64, 512, 0, stream>>>(hc, Wl + i * 128 * 128,
                                                Wr + i * 128 * 128, xl, xr);
        gat_aggregate5<<<NN / 16, 256, 0, stream>>>(xl, xr, bucket, cursor,
                                                    att + i * 128, bb + i * 128, hn);
        float* tmp = hc; hc = hn; hn = tmp;
    }

    pool_partial<<<BGRAPH * 8, 128, 0, stream>>>(hc, psum, pmax);
    head_kernel<<<BGRAPH, 512, 0, stream>>>(psum, pmax, qW1, qb1, qW2, qb2,
                                            vW1, vb1, vW2, vb2, (float*)d_out);
}

// Round 7
// 381.653 us; speedup vs baseline: 1.0629x; 1.0629x over previous
//
#include <hip/hip_runtime.h>
#include <hip/hip_bf16.h>

#define NN 32768      // nodes total
#define EE 524288     // edges total
#define HID 128
#define BGRAPH 64
#define MAXN 512
#define AOUT 512
#define MAXDEG 64     // per-node degree cap (Binomial mean 16: P(deg>64) negligible)

typedef __attribute__((address_space(1))) const unsigned int ga_u32;
typedef __attribute__((address_space(3))) unsigned int lds_u32;

// ---------------- direct bucket build (no CSR scan) ----------------
__global__ void scatter_direct(const int* __restrict__ src, const int* __restrict__ dst,
                               int* __restrict__ cursor, int* __restrict__ bucket) {
    int i = blockIdx.x * blockDim.x + threadIdx.x;
    if (i < EE) {
        int d = dst[i];
        int p = atomicAdd(&cursor[d], 1);
        if (p < MAXDEG) bucket[(size_t)d * MAXDEG + p] = src[i];
    }
}

// ---------------- layer-0 transform (K=12, single chunk) ----------------
template<int KTOT, int KC, int CHUNKS>
__global__ __launch_bounds__(256) void transform3(
    const float* __restrict__ hin, const float* __restrict__ Wl,
    const float* __restrict__ Wr, float* __restrict__ xl, float* __restrict__ xr) {
    __shared__ float wb[2][KC][256];
    __shared__ float ha[2][KC][36];
    int b = blockIdx.x;
    int xcd = b & 7, slot = b >> 3;
    int graph = xcd + 8 * (slot >> 4);
    int chunk = slot & 15;
    int node0 = graph * 512 + chunk * 32;
    int t = threadIdx.x;
    int c32 = t & 31;
    int ng  = t >> 5;
    const float4* wl4g = (const float4*)Wl;
    const float4* wr4g = (const float4*)Wr;
    for (int idx = t; idx < KC * 64; idx += 256) {
        int k = idx >> 6, r = idx & 63;
        float4 v = (r < 32) ? wl4g[k * 32 + r] : wr4g[k * 32 + (r - 32)];
        ((float4*)&wb[0][k][0])[r] = v;
    }
    for (int idx = t; idx < 32 * KC; idx += 256) {
        int m = idx / KC, kk = idx - m * KC;
        ha[0][kk][m] = hin[(size_t)(node0 + m) * KTOT + kk];
    }
    __syncthreads();
    float4 accL[4], accR[4];
#pragma unroll
    for (int m = 0; m < 4; m++) {
        accL[m].x = accL[m].y = accL[m].z = accL[m].w = 0.f;
        accR[m].x = accR[m].y = accR[m].z = accR[m].w = 0.f;
    }
#pragma unroll
    for (int kk = 0; kk < KC; kk++) {
        float4 wl = ((const float4*)&wb[0][kk][0])[c32];
        float4 wr = ((const float4*)&wb[0][kk][128])[c32];
        float4 hv = *(const float4*)&ha[0][kk][ng * 4];
        accL[0].x = fmaf(hv.x, wl.x, accL[0].x); accL[0].y = fmaf(hv.x, wl.y, accL[0].y);
        accL[0].z = fmaf(hv.x, wl.z, accL[0].z); accL[0].w = fmaf(hv.x, wl.w, accL[0].w);
        accL[1].x = fmaf(hv.y, wl.x, accL[1].x); accL[1].y = fmaf(hv.y, wl.y, accL[1].y);
        accL[1].z = fmaf(hv.y, wl.z, accL[1].z); accL[1].w = fmaf(hv.y, wl.w, accL[1].w);
        accL[2].x = fmaf(hv.z, wl.x, accL[2].x); accL[2].y = fmaf(hv.z, wl.y, accL[2].y);
        accL[2].z = fmaf(hv.z, wl.z, accL[2].z); accL[2].w = fmaf(hv.z, wl.w, accL[2].w);
        accL[3].x = fmaf(hv.w, wl.x, accL[3].x); accL[3].y = fmaf(hv.w, wl.y, accL[3].y);
        accL[3].z = fmaf(hv.w, wl.z, accL[3].z); accL[3].w = fmaf(hv.w, wl.w, accL[3].w);
        accR[0].x = fmaf(hv.x, wr.x, accR[0].x); accR[0].y = fmaf(hv.x, wr.y, accR[0].y);
        accR[0].z = fmaf(hv.x, wr.z, accR[0].z); accR[0].w = fmaf(hv.x, wr.w, accR[0].w);
        accR[1].x = fmaf(hv.y, wr.x, accR[1].x); accR[1].y = fmaf(hv.y, wr.y, accR[1].y);
        accR[1].z = fmaf(hv.y, wr.z, accR[1].z); accR[1].w = fmaf(hv.y, wr.w, accR[1].w);
        accR[2].x = fmaf(hv.z, wr.x, accR[2].x); accR[2].y = fmaf(hv.z, wr.y, accR[2].y);
        accR[2].z = fmaf(hv.z, wr.z, accR[2].z); accR[2].w = fmaf(hv.z, wr.w, accR[2].w);
        accR[3].x = fmaf(hv.w, wr.x, accR[3].x); accR[3].y = fmaf(hv.w, wr.y, accR[3].y);
        accR[3].z = fmaf(hv.w, wr.z, accR[3].z); accR[3].w = fmaf(hv.w, wr.w, accR[3].w);
    }
    float4* xlo = (float4*)xl;
    float4* xro = (float4*)xr;
#pragma unroll
    for (int m = 0; m < 4; m++) {
        int n = node0 + ng * 4 + m;
        xlo[n * 32 + c32] = accL[m];
        xro[n * 32 + c32] = accR[m];
    }
}

// ---------------- main transform (K=128): async-DMA W staging ----------------
__global__ __launch_bounds__(512) void transform4(
    const float* __restrict__ hin, const float* __restrict__ Wl,
    const float* __restrict__ Wr, float* __restrict__ xl, float* __restrict__ xr) {
    __shared__ float wlb[2][16][128];
    __shared__ float wrb[2][16][128];
    __shared__ float ha[2][16][68];
    int b = blockIdx.x;
    int xcd = b & 7, slot = b >> 3;
    int graph = xcd + 8 * (slot >> 3);
    int chunk = slot & 7;
    int node0 = graph * 512 + chunk * 64;
    int t = threadIdx.x;
    int w = t >> 6, lane = t & 63;
    int c32 = t & 31, ng = t >> 5;

    float h0, h1;
    int i0 = t, i1 = t + 512;
    int m0 = i0 >> 4, k0 = i0 & 15;
    int m1 = i1 >> 4, k1 = i1 & 15;

    auto loadH = [&](int kc) {
        h0 = hin[(size_t)(node0 + m0) * 128 + kc + k0];
        h1 = hin[(size_t)(node0 + m1) * 128 + kc + k1];
    };
    auto writeH = [&](int buf) {
        ha[buf][k0][m0] = h0;
        ha[buf][k1][m1] = h1;
    };
    auto dmaW = [&](int buf, int kc) {
        const float* gl = Wl + kc * 128 + w * 256 + lane * 4;
        const float* gr = Wr + kc * 128 + w * 256 + lane * 4;
        float* ll = &wlb[buf][0][0] + w * 256;
        float* lr = &wrb[buf][0][0] + w * 256;
        __builtin_amdgcn_global_load_lds((ga_u32*)gl, (lds_u32*)ll, 16, 0, 0);
        __builtin_amdgcn_global_load_lds((ga_u32*)gr, (lds_u32*)lr, 16, 0, 0);
    };

    float4 accL[4], accR[4];
#pragma unroll
    for (int m = 0; m < 4; m++) {
        accL[m].x = accL[m].y = accL[m].z = accL[m].w = 0.f;
        accR[m].x = accR[m].y = accR[m].z = accR[m].w = 0.f;
    }

    loadH(0);
    dmaW(0, 0);
    writeH(0);
    __syncthreads();
    int buf = 0;
    for (int c = 0; c < 8; c++) {
        if (c < 7) { loadH((c + 1) * 16); dmaW(buf ^ 1, (c + 1) * 16); }
#pragma unroll
        for (int kk = 0; kk < 16; kk++) {
            float4 wl = *(const float4*)&wlb[buf][kk][c32 * 4];
            float4 wr = *(const float4*)&wrb[buf][kk][c32 * 4];
            float4 hv = *(const float4*)&ha[buf][kk][ng * 4];
            accL[0].x = fmaf(hv.x, wl.x, accL[0].x); accL[0].y = fmaf(hv.x, wl.y, accL[0].y);
            accL[0].z = fmaf(hv.x, wl.z, accL[0].z); accL[0].w = fmaf(hv.x, wl.w, accL[0].w);
            accL[1].x = fmaf(hv.y, wl.x, accL[1].x); accL[1].y = fmaf(hv.y, wl.y, accL[1].y);
            accL[1].z = fmaf(hv.y, wl.z, accL[1].z); accL[1].w = fmaf(hv.y, wl.w, accL[1].w);
            accL[2].x = fmaf(hv.z, wl.x, accL[2].x); accL[2].y = fmaf(hv.z, wl.y, accL[2].y);
            accL[2].z = fmaf(hv.z, wl.z, accL[2].z); accL[2].w = fmaf(hv.z, wl.w, accL[2].w);
            accL[3].x = fmaf(hv.w, wl.x, accL[3].x); accL[3].y = fmaf(hv.w, wl.y, accL[3].y);
            accL[3].z = fmaf(hv.w, wl.z, accL[3].z); accL[3].w = fmaf(hv.w, wl.w, accL[3].w);
            accR[0].x = fmaf(hv.x, wr.x, accR[0].x); accR[0].y = fmaf(hv.x, wr.y, accR[0].y);
            accR[0].z = fmaf(hv.x, wr.z, accR[0].z); accR[0].w = fmaf(hv.x, wr.w, accR[0].w);
            accR[1].x = fmaf(hv.y, wr.x, accR[1].x); accR[1].y = fmaf(hv.y, wr.y, accR[1].y);
            accR[1].z = fmaf(hv.y, wr.z, accR[1].z); accR[1].w = fmaf(hv.y, wr.w, accR[1].w);
            accR[2].x = fmaf(hv.z, wr.x, accR[2].x); accR[2].y = fmaf(hv.z, wr.y, accR[2].y);
            accR[2].z = fmaf(hv.z, wr.z, accR[2].z); accR[2].w = fmaf(hv.z, wr.w, accR[2].w);
            accR[3].x = fmaf(hv.w, wr.x, accR[3].x); accR[3].y = fmaf(hv.w, wr.y, accR[3].y);
            accR[3].z = fmaf(hv.w, wr.z, accR[3].z); accR[3].w = fmaf(hv.w, wr.w, accR[3].w);
        }
        if (c < 7) writeH(buf ^ 1);
        __syncthreads();
        buf ^= 1;
    }

    float4* xlo = (float4*)xl;
    float4* xro = (float4*)xr;
#pragma unroll
    for (int m = 0; m < 4; m++) {
        int n = node0 + ng * 4 + m;
        xlo[n * 32 + c32] = accL[m];
        xro[n * 32 + c32] = accR[m];
    }
}

// ---------------- GATv2 aggregate v6: 4 edges x 16 lanes, small butterfly ----
// lane = el*16 + p16 (el=lane>>4, p16=lane&15). Each lane owns 8 dims
// (p16*8..+7) of one of 4 in-flight edges. Head h = p16>>2.
// Score: 8-dim dot -> shfl_xor(1)+shfl_xor(2) (quad-local) -> exp.
// Accumulate a*v in regs; final reduce = 2 butterfly steps (masks 16,32)
// over 9 values (vs 3 steps x 17 in v5 -> DS-pipe cost halved).
// Softmax shift-invariance: exp(s) directly (s is O(1); verified R1-R6).
__global__ __launch_bounds__(256) void gat_aggregate6(
    const float* __restrict__ xl, const float* __restrict__ xr,
    const int* __restrict__ bucket, const int* __restrict__ cnt,
    const float* __restrict__ att, const float* __restrict__ bias,
    float* __restrict__ hout) {
    int b = blockIdx.x;                 // 2048 blocks
    int xcd = b & 7, slot = b >> 3;
    int graph = xcd + 8 * (slot >> 5);
    int chunk = slot & 31;
    int wid = threadIdx.x >> 6;
    int lane = threadIdx.x & 63;
    int n0 = graph * 512 + chunk * 16 + wid * 4;
    int el  = lane >> 4;   // edge slot (4 in flight)
    int p16 = lane & 15;   // 8-dim slice; head = p16>>2

    const float4* xl4 = (const float4*)xl;
    const float4* xr4 = (const float4*)xr;
    const float4* att4 = (const float4*)att;
    const float4* bias4 = (const float4*)bias;
    float4* out4 = (float4*)hout;
    float4 at0 = att4[p16 * 2];
    float4 at1 = att4[p16 * 2 + 1];
    float4 a20, a21;
    a20.x = 0.2f * at0.x; a20.y = 0.2f * at0.y; a20.z = 0.2f * at0.z; a20.w = 0.2f * at0.w;
    a21.x = 0.2f * at1.x; a21.y = 0.2f * at1.y; a21.z = 0.2f * at1.z; a21.w = 0.2f * at1.w;

    int4 cnts = *(const int4*)&cnt[n0];

#pragma unroll
    for (int ni = 0; ni < 4; ni++) {
        int n = n0 + ni;
        int nE = (ni == 0) ? cnts.x : (ni == 1) ? cnts.y : (ni == 2) ? cnts.z : cnts.w;
        nE = (nE > MAXDEG) ? MAXDEG : nE;
        int nC = (nE + 3) >> 2;
        float4 xr0 = xr4[(size_t)n * 32 + p16 * 2];
        float4 xr1 = xr4[(size_t)n * 32 + p16 * 2 + 1];
        float4 acc0, acc1;
        acc0.x = acc0.y = acc0.z = acc0.w = 0.f;
        acc1.x = acc1.y = acc1.z = acc1.w = 0.f;
        float den = 0.f;
        const int* brow = bucket + (size_t)n * MAXDEG;
        for (int c = 0; c < nC; c++) {
            int e = c * 4 + el;
            int s = (e < nE) ? brow[e] : n;
            const float4* row = xl4 + (size_t)s * 32 + p16 * 2;
            float4 v0 = row[0];
            float4 v1 = row[1];
            float t = 0.f, u;
            u = v0.x + xr0.x; t = fmaf((u >= 0.f) ? at0.x : a20.x, u, t);
            u = v0.y + xr0.y; t = fmaf((u >= 0.f) ? at0.y : a20.y, u, t);
            u = v0.z + xr0.z; t = fmaf((u >= 0.f) ? at0.z : a20.z, u, t);
            u = v0.w + xr0.w; t = fmaf((u >= 0.f) ? at0.w : a20.w, u, t);
            u = v1.x + xr1.x; t = fmaf((u >= 0.f) ? at1.x : a21.x, u, t);
            u = v1.y + xr1.y; t = fmaf((u >= 0.f) ? at1.y : a21.y, u, t);
            u = v1.z + xr1.z; t = fmaf((u >= 0.f) ? at1.z : a21.z, u, t);
            u = v1.w + xr1.w; t = fmaf((u >= 0.f) ? at1.w : a21.w, u, t);
            t += __shfl_xor(t, 1);      // quad-local: sum the 4 lanes of this head
            t += __shfl_xor(t, 2);
            float a = (e < nE) ? __expf(t) : 0.f;
            den += a;
            acc0.x = fmaf(a, v0.x, acc0.x); acc0.y = fmaf(a, v0.y, acc0.y);
            acc0.z = fmaf(a, v0.z, acc0.z); acc0.w = fmaf(a, v0.w, acc0.w);
            acc1.x = fmaf(a, v1.x, acc1.x); acc1.y = fmaf(a, v1.y, acc1.y);
            acc1.z = fmaf(a, v1.z, acc1.z); acc1.w = fmaf(a, v1.w, acc1.w);
        }
        // reduce across the 4 edge groups (lane bits 4,5): 2 steps x 9 values
#pragma unroll
        for (int m = 16; m <= 32; m <<= 1) {
            acc0.x += __shfl_xor(acc0.x, m); acc0.y += __shfl_xor(acc0.y, m);
            acc0.z += __shfl_xor(acc0.z, m); acc0.w += __shfl_xor(acc0.w, m);
            acc1.x += __shfl_xor(acc1.x, m); acc1.y += __shfl_xor(acc1.y, m);
            acc1.z += __shfl_xor(acc1.z, m); acc1.w += __shfl_xor(acc1.w, m);
            den += __shfl_xor(den, m);
        }
        if (el == 0) {
            float rden = 1.0f / fmaxf(den, 1e-16f);
            float4 b0v = bias4[p16 * 2];
            float4 b1v = bias4[p16 * 2 + 1];
            float4 o0, o1;
            o0.x = fmaxf(fmaf(acc0.x, rden, b0v.x), 0.f);
            o0.y = fmaxf(fmaf(acc0.y, rden, b0v.y), 0.f);
            o0.z = fmaxf(fmaf(acc0.z, rden, b0v.z), 0.f);
            o0.w = fmaxf(fmaf(acc0.w, rden, b0v.w), 0.f);
            o1.x = fmaxf(fmaf(acc1.x, rden, b1v.x), 0.f);
            o1.y = fmaxf(fmaf(acc1.y, rden, b1v.y), 0.f);
            o1.z = fmaxf(fmaf(acc1.z, rden, b1v.z), 0.f);
            o1.w = fmaxf(fmaf(acc1.w, rden, b1v.w), 0.f);
            out4[(size_t)n * 32 + p16 * 2]     = o0;
            out4[(size_t)n * 32 + p16 * 2 + 1] = o1;
        }
    }
}

// ---------------- pooling stage 1 ----------------
__global__ __launch_bounds__(128) void pool_partial(const float* __restrict__ h,
                                                    float* __restrict__ psum,
                                                    float* __restrict__ pmax) {
    int g = blockIdx.x >> 3;
    int c = blockIdx.x & 7;
    int d = threadIdx.x;
    const float* base = h + (size_t)(g * MAXN + c * 64) * 128;
    float s = 0.f, m = -1e30f;
    for (int i = 0; i < 64; i++) {
        float v = base[i * 128 + d];
        s += v;
        m = fmaxf(m, v);
    }
    psum[blockIdx.x * 128 + d] = s;
    pmax[blockIdx.x * 128 + d] = m;
}

// ---------------- pool-final + dueling head, one block per graph ----------------
__global__ __launch_bounds__(512) void head_kernel(
    const float* __restrict__ psum, const float* __restrict__ pmax,
    const float* __restrict__ qW1, const float* __restrict__ qb1,
    const float* __restrict__ qW2, const float* __restrict__ qb2,
    const float* __restrict__ vW1, const float* __restrict__ vb1,
    const float* __restrict__ vW2, const float* __restrict__ vb2,
    float* __restrict__ qout) {
    __shared__ float gs[256];
    __shared__ float hq[128];
    __shared__ float hv[128];
    __shared__ float red[512];
    int b = blockIdx.x, t = threadIdx.x;
    if (t < 128) {
        float s = 0.f, m = -1e30f;
#pragma unroll
        for (int c = 0; c < 8; c++) {
            s += psum[(b * 8 + c) * 128 + t];
            m = fmaxf(m, pmax[(b * 8 + c) * 128 + t]);
        }
        gs[t] = s * (1.0f / 512.0f);
        gs[128 + t] = m;
    }
    __syncthreads();
    if (t < 128) {
        float acc = qb1[t];
        for (int k = 0; k < 256; k++) acc = fmaf(gs[k], qW1[k * 128 + t], acc);
        hq[t] = fmaxf(acc, 0.f);
    } else if (t < 256) {
        int tt = t - 128;
        float acc = vb1[tt];
        for (int k = 0; k < 256; k++) acc = fmaf(gs[k], vW1[k * 128 + tt], acc);
        hv[tt] = fmaxf(acc, 0.f);
    }
    __syncthreads();
    float adv = qb2[t];
    for (int k = 0; k < 128; k++) adv = fmaf(hq[k], qW2[k * 512 + t], adv);
    red[t] = (t < 128) ? hv[t] * vW2[t] : 0.f;
    __syncthreads();
    for (int off = 256; off > 0; off >>= 1) {
        if (t < off) red[t] += red[t + off];
        __syncthreads();
    }
    float val = red[0] + vb2[0];
    __syncthreads();
    red[t] = adv;
    __syncthreads();
    for (int off = 256; off > 0; off >>= 1) {
        if (t < off) red[t] += red[t + off];
        __syncthreads();
    }
    float mean_adv = red[0] * (1.0f / 512.0f);
    qout[b * 512 + t] = val + adv - mean_adv;
}

extern "C" void kernel_launch(void* const* d_in, const int* in_sizes, int n_in,
                              void* d_out, int out_size, void* d_ws, size_t ws_size,
                              hipStream_t stream) {
    const float* x        = (const float*)d_in[0];
    const int* edge_src   = (const int*)d_in[1];
    const int* edge_dst   = (const int*)d_in[2];
    const float* Wl0 = (const float*)d_in[4];
    const float* Wr0 = (const float*)d_in[5];
    const float* att0 = (const float*)d_in[6];
    const float* b0 = (const float*)d_in[7];
    const float* Wl = (const float*)d_in[8];
    const float* Wr = (const float*)d_in[9];
    const float* att = (const float*)d_in[10];
    const float* bb = (const float*)d_in[11];
    const float* qW1 = (const float*)d_in[12];
    const float* qb1 = (const float*)d_in[13];
    const float* qW2 = (const float*)d_in[14];
    const float* qb2 = (const float*)d_in[15];
    const float* vW1 = (const float*)d_in[16];
    const float* vb1 = (const float*)d_in[17];
    const float* vW2 = (const float*)d_in[18];
    const float* vb2 = (const float*)d_in[19];

    int* cursor  = (int*)d_ws;                 // NN
    int* bucket  = cursor + NN;                // NN*MAXDEG (8 MB)
    float* fbase = (float*)(bucket + (size_t)NN * MAXDEG);
    float* hbuf0 = fbase;                      // NN*128
    float* hbuf1 = hbuf0 + NN * 128;
    float* xl    = hbuf1 + NN * 128;
    float* xr    = xl + NN * 128;
    float* psum  = xr + NN * 128;
    float* pmax  = psum + BGRAPH * 8 * 128;

    hipMemsetAsync(cursor, 0, NN * sizeof(int), stream);
    scatter_direct<<<EE / 256, 256, 0, stream>>>(edge_src, edge_dst, cursor, bucket);

    transform3<12, 12, 1><<<NN / 32, 256, 0, stream>>>(x, Wl0, Wr0, xl, xr);
    gat_aggregate6<<<NN / 16, 256, 0, stream>>>(xl, xr, bucket, cursor, att0, b0, hbuf0);

    float* hc = hbuf0;
    float* hn = hbuf1;
    for (int i = 0; i < 3; i++) {
        transform4<<<NN / 64, 512, 0, stream>>>(hc, Wl + i * 128 * 128,
                                                Wr + i * 128 * 128, xl, xr);
        gat_aggregate6<<<NN / 16, 256, 0, stream>>>(xl, xr, bucket, cursor,
                                                    att + i * 128, bb + i * 128, hn);
        float* tmp = hc; hc = hn; hn = tmp;
    }

    pool_partial<<<BGRAPH * 8, 128, 0, stream>>>(hc, psum, pmax);
    head_kernel<<<BGRAPH, 512, 0, stream>>>(psum, pmax, qW1, qb1, qW2, qb2,
                                            vW1, vb1, vW2, vb2, (float*)d_out);
}